// Round 12
// baseline (239.188 us; speedup 1.0000x reference)
//
#include <hip/hip_runtime.h>
#include <hip/hip_bf16.h>

#define NNODES 100000
#define NEDGES 1600000
#define IN_DIM 64
#define HID_DIM 128

#define BUKSHIFT 8                   // 256 nodes per bucket (R10 geometry)
#define BUKNODES 256
#define NBUK ((NNODES + 255) >> 8)   // 391 buckets
#define BUKCAP 4608                  // mean 4094 + 8 sigma; deterministic input -> safe
#define CHUNK 4096                   // edges per partition block (runs ~10.5 edges/bucket)
#define TILE_N 128                   // nodes per k_gmlp block
#define SATS 132                     // sAt stride: 128+4 swizzle pad

// Edge packing: src in bits 0..23, dst-within-bucket (8 bits) in 24..31.
#define EPACK(s, d)  ((s) | (((d) & 255) << 24))
#define ESRC(p)      ((p) & 0x00FFFFFF)
#define EDL(p)       ((int)(((unsigned)(p)) >> 24))

// bf16 helpers (RNE round; unpack = shift/mask only)
__device__ inline unsigned short f2bf(float f) {
    unsigned u = __float_as_uint(f);
    u += 0x7fff + ((u >> 16) & 1);
    return (unsigned short)(u >> 16);
}
__device__ inline unsigned bfpack2(float a, float b) {
    return (unsigned)f2bf(a) | ((unsigned)f2bf(b) << 16);
}
__device__ inline float bflo(unsigned u) { return __uint_as_float(u << 16); }
__device__ inline float bfhi(unsigned u) { return __uint_as_float(u & 0xffff0000u); }

// ---------- phase 1: bucket-partition edges into packed ebuf ----------
// R10 geometry: 391 blocks x 4096 edges, 256-node buckets.
__global__ __launch_bounds__(1024, 8) void k_part(const int* __restrict__ src,
                                                  const int* __restrict__ dst,
                                                  int* __restrict__ gbcur,
                                                  int* __restrict__ ebuf, int E) {
    __shared__ int stage[CHUNK];               // 16 KB packed edges
    __shared__ unsigned short bukof[CHUNK];    // 8 KB bucket id per slot
    __shared__ int hist[NBUK];
    __shared__ int scanb[NBUK];
    __shared__ int basep[NBUK];
    __shared__ int sb[2][512];
    int t = threadIdx.x;
    int start = blockIdx.x * CHUNK;
    int n = E - start; if (n > CHUNK) n = CHUNK;

    if (t < NBUK) hist[t] = 0;
    __syncthreads();

    int myb[4], myr[4], mp[4];
    #pragma unroll
    for (int i = 0; i < 4; i++) {
        int c = t + i * 1024;
        if (c < n) {
            int s = src[start + c];
            int d = dst[start + c];
            int b = d >> BUKSHIFT;
            myb[i] = b;
            mp[i]  = EPACK(s, d);
            myr[i] = atomicAdd(&hist[b], 1);   // rank within (block,bucket)
        } else myb[i] = -1;
    }
    __syncthreads();

    // parallel exclusive scan of hist[NBUK] (NBUK=391 < 512)
    {
        int v = (t < NBUK) ? hist[t] : 0;
        if (t < 512) sb[0][t] = v;
        __syncthreads();
        int pin = 0;
        for (int ofs = 1; ofs < 512; ofs <<= 1) {
            if (t < 512) sb[pin ^ 1][t] = (t >= ofs) ? sb[pin][t] + sb[pin][t - ofs]
                                                     : sb[pin][t];
            __syncthreads();
            pin ^= 1;
        }
        if (t < NBUK) scanb[t] = sb[pin][t] - v;
    }

    if (t < NBUK) {                            // claim region space per bucket
        int h = hist[t];
        basep[t] = h ? (t * BUKCAP + atomicAdd(&gbcur[t], h)) : 0;
    }
    __syncthreads();

    #pragma unroll
    for (int i = 0; i < 4; i++) {              // scatter into LDS stage
        if (myb[i] >= 0) {
            int p = scanb[myb[i]] + myr[i];
            stage[p] = mp[i];
            bukof[p] = (unsigned short)myb[i];
        }
    }
    __syncthreads();

    for (int c = t; c < n; c += 1024) {        // positional writeout in runs
        int b = bukof[c];
        ebuf[basep[b] + (c - scanb[b])] = stage[c];
    }
}

// ---------- phase 2: degrees + dinv + off/end + csr fill + x->xsb convert ----
__global__ __launch_bounds__(1024, 8) void k_bfill(const int* __restrict__ gbcur,
                                                   const int* __restrict__ ebuf,
                                                   const float* __restrict__ x,
                                                   int* __restrict__ off,
                                                   int* __restrict__ nend,
                                                   float* __restrict__ dinv,
                                                   int* __restrict__ csr,
                                                   unsigned* __restrict__ xsb, int N) {
    __shared__ int sEdge[BUKCAP];              // 18.4 KB
    __shared__ int lcnt[BUKNODES];
    __shared__ int sbuf[2][BUKNODES];
    __shared__ int cur[BUKNODES];
    __shared__ float sdinv[BUKNODES];
    int b = blockIdx.x, t = threadIdx.x;
    int nbase = b << BUKSHIFT;
    int rbase = b * BUKCAP;
    int cntb = gbcur[b];                       // final bucket edge count
    if (t < BUKNODES) lcnt[t] = 0;
    __syncthreads();
    for (int i = t; i < cntb; i += 1024) {     // load + count in one pass
        int p = ebuf[rbase + i];
        sEdge[i] = p;
        atomicAdd(&lcnt[EDL(p)], 1);
    }
    __syncthreads();
    int v = (t < BUKNODES) ? lcnt[t] : 0;
    if (t < BUKNODES) sbuf[0][t] = v;
    __syncthreads();
    int pin = 0;
    for (int ofs = 1; ofs < BUKNODES; ofs <<= 1) {
        if (t < BUKNODES) sbuf[pin ^ 1][t] = (t >= ofs) ? sbuf[pin][t] + sbuf[pin][t - ofs]
                                                        : sbuf[pin][t];
        __syncthreads();
        pin ^= 1;
    }
    if (t < BUKNODES) {
        int o = rbase + sbuf[pin][t] - v;      // region base + exclusive scan
        int nid = nbase + t;
        float dv = rsqrtf((float)v + 1.0f);
        sdinv[t] = dv;
        if (nid < N) {
            off[nid]  = o;
            nend[nid] = o + v;
            dinv[nid] = dv;
        }
        cur[t] = o;
    }
    __syncthreads();
    for (int i = t; i < cntb; i += 1024) {     // fill csr from LDS
        int p = sEdge[i];
        int pos = atomicAdd(&cur[EDL(p)], 1);
        csr[pos] = ESRC(p);
    }
    // fused convert: xsb[n] = bf16(x[n] * dinv[n]) for this bucket's nodes
    for (int i = t; i < BUKNODES * 16; i += 1024) {
        int nl = i >> 4;
        int nid = nbase + nl;
        if (nid < N) {
            float dv = sdinv[nl];
            float4 vx = ((const float4*)x)[(size_t)nid * 16 + (i & 15)];
            uint2 u;
            u.x = bfpack2(vx.x * dv, vx.y * dv);
            u.y = bfpack2(vx.z * dv, vx.w * dv);
            ((uint2*)xsb)[(size_t)nid * 16 + (i & 15)] = u;
        }
    }
}

// ---------- fused layer-1 gather + MLP ----------
// Block = 128 nodes, 512 threads (8 waves). Phase 1: each wave gathers 16
// nodes' agg rows (bf16 xs, 8 lanes/edge x 16 B loads) and writes them fp32
// STRAIGHT INTO the GEMM A-tile in LDS (rotation-swizzled, conflict-free) --
// the 12.8 MB aggb global round-trip of R10/R11 is gone. Phase 2: 128x(64)x128
// GEMM + relu + W2 dot, zd = result * dinv. Across blocks the latency-bound
// gather and VALU-bound GEMM phases co-schedule on each CU.
// LDS 66 KB -> 2 blocks/CU = 16 waves/CU (same hiding as standalone gather64).
__global__ __launch_bounds__(512) void k_gmlp(const int* __restrict__ off,
                                              const int* __restrict__ nend,
                                              const int* __restrict__ csr,
                                              const uint4* __restrict__ xsb,
                                              const float* __restrict__ dinv,
                                              const float* __restrict__ W1,
                                              const float* __restrict__ b1,
                                              const float* __restrict__ W2,
                                              float* __restrict__ zd, int n_nodes) {
    __shared__ float sW1[IN_DIM * HID_DIM];   // 32 KB, [k][j]
    __shared__ float sAt[IN_DIM * SATS];      // 33.8 KB, [k][node], swizzle pad
    __shared__ float sW2[HID_DIM];
    __shared__ float sb1[HID_DIM];
    int t = threadIdx.x;

    {   // stage W1: 2048 float4 over 512 threads
        const float4* W14 = (const float4*)W1;
        float4* sW14 = (float4*)sW1;
        #pragma unroll
        for (int i = 0; i < 4; i++) sW14[t + i * 512] = W14[t + i * 512];
    }
    if (t < HID_DIM) { sW2[t] = W2[t]; sb1[t] = b1[t]; }

    // ---- phase 1: gather agg rows into sAt ----
    int node0 = blockIdx.x * TILE_N;
    int wv = t >> 6;                           // wave 0..7 -> 16 nodes each
    int lane = t & 63;
    int c = lane & 7;                          // channel octet (8 bf16 = 16 B)
    int g = lane >> 3;                         // edge sub-slot
    for (int nl = wv * 16; nl < wv * 16 + 16; nl++) {
        int n = node0 + nl;
        float f0[8] = {0, 0, 0, 0, 0, 0, 0, 0};
        float f1[8] = {0, 0, 0, 0, 0, 0, 0, 0};
        float dd = 0.0f;
        if (n < n_nodes) {                     // wave-uniform branch
            int beg = off[n], fin = nend[n];
            dd = dinv[n];
            if (g == 0) {                      // self term xs[n]
                uint4 u = xsb[(size_t)n * 8 + c];
                f0[0] = bflo(u.x); f0[1] = bfhi(u.x); f0[2] = bflo(u.y); f0[3] = bfhi(u.y);
                f0[4] = bflo(u.z); f0[5] = bfhi(u.z); f0[6] = bflo(u.w); f0[7] = bfhi(u.w);
            }
            for (int base = beg; base < fin; base += 64) {
                int nn = fin - base; if (nn > 64) nn = 64;
                int idx = (lane < nn) ? csr[base + lane] : 0;
                int j = 0;
                for (; j + 16 <= nn; j += 16) {    // 16 edges: 2 loads in flight
                    int sa = __shfl(idx, j + g);
                    int sb = __shfl(idx, j + 8 + g);
                    uint4 ua = xsb[(size_t)sa * 8 + c];
                    uint4 ub = xsb[(size_t)sb * 8 + c];
                    f0[0] += bflo(ua.x); f0[1] += bfhi(ua.x); f0[2] += bflo(ua.y); f0[3] += bfhi(ua.y);
                    f0[4] += bflo(ua.z); f0[5] += bfhi(ua.z); f0[6] += bflo(ua.w); f0[7] += bfhi(ua.w);
                    f1[0] += bflo(ub.x); f1[1] += bfhi(ub.x); f1[2] += bflo(ub.y); f1[3] += bfhi(ub.y);
                    f1[4] += bflo(ub.z); f1[5] += bfhi(ub.z); f1[6] += bflo(ub.w); f1[7] += bfhi(ub.w);
                }
                for (; j < nn; j += 8) {           // tail, 8-wide predicated
                    int rem = nn - j;
                    int sa = __shfl(idx, j + g);
                    if (g < rem) {
                        uint4 ua = xsb[(size_t)sa * 8 + c];
                        f0[0] += bflo(ua.x); f0[1] += bfhi(ua.x); f0[2] += bflo(ua.y); f0[3] += bfhi(ua.y);
                        f0[4] += bflo(ua.z); f0[5] += bfhi(ua.z); f0[6] += bflo(ua.w); f0[7] += bfhi(ua.w);
                    }
                }
            }
            #pragma unroll
            for (int i = 0; i < 8; i++) f0[i] += f1[i];
            #pragma unroll
            for (int m = 8; m < 64; m <<= 1) {     // combine the 8 g-slots
                #pragma unroll
                for (int i = 0; i < 8; i++) f0[i] += __shfl_xor(f0[i], m);
            }
        }
        if (g == 0) {                          // lanes c=0..7: channels 8c..8c+7
            #pragma unroll
            for (int i0 = 0; i0 < 8; i0++) {
                int i = (i0 + c) & 7;          // rotation: banks 4i+nl, distinct
                sAt[(c * 8 + i) * SATS + nl] = f0[i] * dd;
            }
        }
    }
    __syncthreads();

    // ---- phase 2: GEMM + relu + W2 ----
    int tx = t & 15;                           // hidden quad
    int ty = t >> 4;                           // node quad (0..31)
    float zpart[4] = {0, 0, 0, 0};
    #pragma unroll
    for (int jh = 0; jh < 2; jh++) {
        int jbase = jh * 64 + tx * 4;
        float4 bv = *(const float4*)&sb1[jbase];
        float acc[4][4];
        #pragma unroll
        for (int i = 0; i < 4; i++) {
            acc[i][0] = bv.x; acc[i][1] = bv.y; acc[i][2] = bv.z; acc[i][3] = bv.w;
        }
        #pragma unroll 4
        for (int k = 0; k < IN_DIM; k++) {
            float4 w = *(const float4*)&sW1[k * HID_DIM + jbase];
            float4 a = *(const float4*)&sAt[k * SATS + ty * 4];   // 16B aligned
            float av[4] = {a.x, a.y, a.z, a.w};
            #pragma unroll
            for (int i = 0; i < 4; i++) {
                acc[i][0] += av[i] * w.x;
                acc[i][1] += av[i] * w.y;
                acc[i][2] += av[i] * w.z;
                acc[i][3] += av[i] * w.w;
            }
        }
        float4 w2v = *(const float4*)&sW2[jbase];
        #pragma unroll
        for (int i = 0; i < 4; i++) {
            float s = 0.0f;
            s += (acc[i][0] > 0.f ? acc[i][0] : 0.f) * w2v.x;
            s += (acc[i][1] > 0.f ? acc[i][1] : 0.f) * w2v.y;
            s += (acc[i][2] > 0.f ? acc[i][2] : 0.f) * w2v.z;
            s += (acc[i][3] > 0.f ? acc[i][3] : 0.f) * w2v.w;
            zpart[i] += s;
        }
    }
    #pragma unroll
    for (int m = 1; m < 16; m <<= 1) {         // reduce over the 16 tx lanes
        #pragma unroll
        for (int i = 0; i < 4; i++) zpart[i] += __shfl_xor(zpart[i], m);
    }
    if (tx == 0) {
        #pragma unroll
        for (int i = 0; i < 4; i++) {
            int n = node0 + ty * 4 + i;
            if (n < n_nodes) zd[n] = zpart[i] * dinv[n];   // pre-scaled for layer 2
        }
    }
}

// ---------- layer-2 aggregation: 8 lanes per node ----------
// out[n] = dd*(zd[n] + sum_s zd[s]) + b2
__global__ __launch_bounds__(1024, 8) void k_gather1(const int* __restrict__ off,
                                                     const int* __restrict__ nend,
                                                     const int* __restrict__ csr,
                                                     const float* __restrict__ zd,
                                                     const float* __restrict__ dinv,
                                                     const float* __restrict__ b2,
                                                     float* __restrict__ out, int n_nodes) {
    int tid = blockIdx.x * 1024 + threadIdx.x;
    int n = tid >> 3;
    int l = tid & 7;
    if (n >= n_nodes) return;
    int beg = off[n], fin = nend[n];
    float a0 = 0.0f, a1 = 0.0f;
    for (int i = beg + l; i < fin; i += 16) {
        a0 += zd[csr[i]];
        int i2 = i + 8;
        if (i2 < fin) a1 += zd[csr[i2]];
    }
    float a = a0 + a1;
    a += __shfl_xor(a, 1);
    a += __shfl_xor(a, 2);
    a += __shfl_xor(a, 4);
    if (l == 0) out[n] = (a + zd[n]) * dinv[n] + b2[0];
}

extern "C" void kernel_launch(void* const* d_in, const int* in_sizes, int n_in,
                              void* d_out, int out_size, void* d_ws, size_t ws_size,
                              hipStream_t stream) {
    const float* x  = (const float*)d_in[0];
    const int*   ei = (const int*)d_in[1];     // [2, E] int32
    const float* W1 = (const float*)d_in[2];
    const float* b1 = (const float*)d_in[3];
    const float* W2 = (const float*)d_in[4];
    const float* b2 = (const float*)d_in[5];
    float* out = (float*)d_out;

    const int N = NNODES;
    const int E = NEDGES;
    const int* src = ei;
    const int* dst = ei + E;

    // workspace (~29 MB):
    // gbcur | off | nend | dinv | zd | csr[NBUK*BUKCAP] | xsb(bf16) | ebuf
    int* gbcur = (int*)d_ws;                   // [NBUK] (padded to 512)
    int* off   = gbcur + 512;                  // [N]
    int* nend  = off + N;                      // [N]
    float* dinv = (float*)(nend + N);          // [N]
    float* zd   = dinv + N;                    // [N]
    int* csr    = (int*)(zd + N);              // [NBUK*BUKCAP] gapped (7.2 MB)
    size_t o1 = ((size_t)((char*)(csr + NBUK * BUKCAP) - (char*)d_ws) + 127) & ~(size_t)127;
    unsigned* xsb = (unsigned*)((char*)d_ws + o1);        // [N*32] = 12.8 MB
    size_t o2 = o1 + (size_t)N * 128;
    int*   ebuf = (int*)((char*)d_ws + o2);               // [NBUK*BUKCAP] 7.2 MB

    hipMemsetAsync(gbcur, 0, 512 * sizeof(int), stream);
    k_part<<<(E + CHUNK - 1) / CHUNK, 1024, 0, stream>>>(src, dst, gbcur, ebuf, E);
    k_bfill<<<NBUK, 1024, 0, stream>>>(gbcur, ebuf, x, off, nend, dinv, csr, xsb, N);
    k_gmlp<<<(N + TILE_N - 1) / TILE_N, 512, 0, stream>>>(off, nend, csr, (const uint4*)xsb,
                                                          dinv, W1, b1, W2, zd, N);
    k_gather1<<<(N * 8 + 1023) / 1024, 1024, 0, stream>>>(off, nend, csr, zd, dinv, b2, out, N);
}

// Round 13
// 198.391 us; speedup vs baseline: 1.2056x; 1.2056x over previous
//
#include <hip/hip_runtime.h>
#include <hip/hip_bf16.h>

#define NNODES 100000
#define NEDGES 1600000
#define IN_DIM 64
#define HID_DIM 128

#define BUKSHIFT 8                   // 256 nodes per bucket (R10 geometry: best measured)
#define BUKNODES 256
#define NBUK ((NNODES + 255) >> 8)   // 391 buckets
#define BUKCAP 4608                  // mean 4094 + 8 sigma; deterministic input -> safe
#define CHUNK 4096                   // edges per partition block (~10.5-edge runs/bucket)
#define TILE_N 128                   // nodes per k_mlp block

// Edge packing: src in bits 0..23, dst-within-bucket (8 bits) in 24..31.
#define EPACK(s, d)  ((s) | (((d) & 255) << 24))
#define ESRC(p)      ((p) & 0x00FFFFFF)
#define EDL(p)       ((int)(((unsigned)(p)) >> 24))

// bf16 helpers (RNE round; unpack = shift/mask only)
__device__ inline unsigned short f2bf(float f) {
    unsigned u = __float_as_uint(f);
    u += 0x7fff + ((u >> 16) & 1);
    return (unsigned short)(u >> 16);
}
__device__ inline unsigned bfpack2(float a, float b) {
    return (unsigned)f2bf(a) | ((unsigned)f2bf(b) << 16);
}
__device__ inline float bflo(unsigned u) { return __uint_as_float(u << 16); }
__device__ inline float bfhi(unsigned u) { return __uint_as_float(u & 0xffff0000u); }

// ---------- phase 1: bucket-partition edges into packed ebuf ----------
__global__ __launch_bounds__(1024, 8) void k_part(const int* __restrict__ src,
                                                  const int* __restrict__ dst,
                                                  int* __restrict__ gbcur,
                                                  int* __restrict__ ebuf, int E) {
    __shared__ int stage[CHUNK];               // 16 KB packed edges
    __shared__ unsigned short bukof[CHUNK];    // 8 KB bucket id per slot
    __shared__ int hist[NBUK];
    __shared__ int scanb[NBUK];
    __shared__ int basep[NBUK];
    __shared__ int sb[2][512];
    int t = threadIdx.x;
    int start = blockIdx.x * CHUNK;
    int n = E - start; if (n > CHUNK) n = CHUNK;

    if (t < NBUK) hist[t] = 0;
    __syncthreads();

    int myb[4], myr[4], mp[4];
    #pragma unroll
    for (int i = 0; i < 4; i++) {
        int c = t + i * 1024;
        if (c < n) {
            int s = src[start + c];
            int d = dst[start + c];
            int b = d >> BUKSHIFT;
            myb[i] = b;
            mp[i]  = EPACK(s, d);
            myr[i] = atomicAdd(&hist[b], 1);   // rank within (block,bucket)
        } else myb[i] = -1;
    }
    __syncthreads();

    // parallel exclusive scan of hist[NBUK] (NBUK=391 < 512)
    {
        int v = (t < NBUK) ? hist[t] : 0;
        if (t < 512) sb[0][t] = v;
        __syncthreads();
        int pin = 0;
        for (int ofs = 1; ofs < 512; ofs <<= 1) {
            if (t < 512) sb[pin ^ 1][t] = (t >= ofs) ? sb[pin][t] + sb[pin][t - ofs]
                                                     : sb[pin][t];
            __syncthreads();
            pin ^= 1;
        }
        if (t < NBUK) scanb[t] = sb[pin][t] - v;
    }

    if (t < NBUK) {                            // claim region space per bucket
        int h = hist[t];
        basep[t] = h ? (t * BUKCAP + atomicAdd(&gbcur[t], h)) : 0;
    }
    __syncthreads();

    #pragma unroll
    for (int i = 0; i < 4; i++) {              // scatter into LDS stage
        if (myb[i] >= 0) {
            int p = scanb[myb[i]] + myr[i];
            stage[p] = mp[i];
            bukof[p] = (unsigned short)myb[i];
        }
    }
    __syncthreads();

    for (int c = t; c < n; c += 1024) {        // positional writeout in runs
        int b = bukof[c];
        ebuf[basep[b] + (c - scanb[b])] = stage[c];
    }
}

// ---------- phase 2: degrees + dinv + off/end + csr fill + x->xsb convert ----
__global__ __launch_bounds__(1024, 8) void k_bfill(const int* __restrict__ gbcur,
                                                   const int* __restrict__ ebuf,
                                                   const float* __restrict__ x,
                                                   int* __restrict__ off,
                                                   int* __restrict__ nend,
                                                   float* __restrict__ dinv,
                                                   int* __restrict__ csr,
                                                   unsigned* __restrict__ xsb, int N) {
    __shared__ int sEdge[BUKCAP];              // 18.4 KB
    __shared__ int lcnt[BUKNODES];
    __shared__ int sbuf[2][BUKNODES];
    __shared__ int cur[BUKNODES];
    __shared__ float sdinv[BUKNODES];
    int b = blockIdx.x, t = threadIdx.x;
    int nbase = b << BUKSHIFT;
    int rbase = b * BUKCAP;
    int cntb = gbcur[b];                       // final bucket edge count
    if (t < BUKNODES) lcnt[t] = 0;
    __syncthreads();
    for (int i = t; i < cntb; i += 1024) {     // load + count in one pass
        int p = ebuf[rbase + i];
        sEdge[i] = p;
        atomicAdd(&lcnt[EDL(p)], 1);
    }
    __syncthreads();
    int v = (t < BUKNODES) ? lcnt[t] : 0;
    if (t < BUKNODES) sbuf[0][t] = v;
    __syncthreads();
    int pin = 0;
    for (int ofs = 1; ofs < BUKNODES; ofs <<= 1) {
        if (t < BUKNODES) sbuf[pin ^ 1][t] = (t >= ofs) ? sbuf[pin][t] + sbuf[pin][t - ofs]
                                                        : sbuf[pin][t];
        __syncthreads();
        pin ^= 1;
    }
    if (t < BUKNODES) {
        int o = rbase + sbuf[pin][t] - v;      // region base + exclusive scan
        int nid = nbase + t;
        float dv = rsqrtf((float)v + 1.0f);
        sdinv[t] = dv;
        if (nid < N) {
            off[nid]  = o;
            nend[nid] = o + v;
            dinv[nid] = dv;
        }
        cur[t] = o;
    }
    __syncthreads();
    for (int i = t; i < cntb; i += 1024) {     // fill csr from LDS
        int p = sEdge[i];
        int pos = atomicAdd(&cur[EDL(p)], 1);
        csr[pos] = ESRC(p);
    }
    // fused convert: xsb[n] = bf16(x[n] * dinv[n]) for this bucket's nodes
    for (int i = t; i < BUKNODES * 16; i += 1024) {
        int nl = i >> 4;
        int nid = nbase + nl;
        if (nid < N) {
            float dv = sdinv[nl];
            float4 vx = ((const float4*)x)[(size_t)nid * 16 + (i & 15)];
            uint2 u;
            u.x = bfpack2(vx.x * dv, vx.y * dv);
            u.y = bfpack2(vx.z * dv, vx.w * dv);
            ((uint2*)xsb)[(size_t)nid * 16 + (i & 15)] = u;
        }
    }
}

// ---------- layer-1 aggregation: wave per node, bf16 rows (R10 version) ----
// agg[n] = dd * ( xs[n] + sum_s xs[s] ), stored bf16. Standalone kernel:
// 25000 blocks -> full occupancy latency hiding (the R12 LDS-fusion dropped
// occupancy to 30% and cost +33 us -- waves-in-flight beat byte-saving here).
__global__ __launch_bounds__(256) void k_gather64(const int* __restrict__ off,
                                                  const int* __restrict__ nend,
                                                  const int* __restrict__ csr,
                                                  const uint4* __restrict__ xsb,
                                                  const float* __restrict__ dinv,
                                                  uint4* __restrict__ aggb, int n_nodes) {
    int tid = blockIdx.x * 256 + threadIdx.x;
    int n = tid >> 6;                          // wave-uniform node
    if (n >= n_nodes) return;
    int lane = threadIdx.x & 63;
    int c = lane & 7;
    int g = lane >> 3;
    int beg = off[n], fin = nend[n];
    float dd = dinv[n];
    float f0[8] = {0, 0, 0, 0, 0, 0, 0, 0};
    float f1[8] = {0, 0, 0, 0, 0, 0, 0, 0};
    if (g == 0) {                              // self term xs[n]
        uint4 u = xsb[(size_t)n * 8 + c];
        f0[0] = bflo(u.x); f0[1] = bfhi(u.x); f0[2] = bflo(u.y); f0[3] = bfhi(u.y);
        f0[4] = bflo(u.z); f0[5] = bfhi(u.z); f0[6] = bflo(u.w); f0[7] = bfhi(u.w);
    }
    for (int base = beg; base < fin; base += 64) {
        int nn = fin - base; if (nn > 64) nn = 64;
        int idx = (lane < nn) ? csr[base + lane] : 0;
        int j = 0;
        for (; j + 16 <= nn; j += 16) {        // 16 edges: 2 loads in flight
            int sa = __shfl(idx, j + g);
            int sb = __shfl(idx, j + 8 + g);
            uint4 ua = xsb[(size_t)sa * 8 + c];
            uint4 ub = xsb[(size_t)sb * 8 + c];
            f0[0] += bflo(ua.x); f0[1] += bfhi(ua.x); f0[2] += bflo(ua.y); f0[3] += bfhi(ua.y);
            f0[4] += bflo(ua.z); f0[5] += bfhi(ua.z); f0[6] += bflo(ua.w); f0[7] += bfhi(ua.w);
            f1[0] += bflo(ub.x); f1[1] += bfhi(ub.x); f1[2] += bflo(ub.y); f1[3] += bfhi(ub.y);
            f1[4] += bflo(ub.z); f1[5] += bfhi(ub.z); f1[6] += bflo(ub.w); f1[7] += bfhi(ub.w);
        }
        for (; j < nn; j += 8) {               // tail, 8-wide predicated
            int rem = nn - j;
            int sa = __shfl(idx, j + g);
            if (g < rem) {
                uint4 ua = xsb[(size_t)sa * 8 + c];
                f0[0] += bflo(ua.x); f0[1] += bfhi(ua.x); f0[2] += bflo(ua.y); f0[3] += bfhi(ua.y);
                f0[4] += bflo(ua.z); f0[5] += bfhi(ua.z); f0[6] += bflo(ua.w); f0[7] += bfhi(ua.w);
            }
        }
    }
    #pragma unroll
    for (int i = 0; i < 8; i++) f0[i] += f1[i];
    #pragma unroll
    for (int m = 8; m < 64; m <<= 1) {         // combine the 8 g-slots
        #pragma unroll
        for (int i = 0; i < 8; i++) f0[i] += __shfl_xor(f0[i], m);
    }
    if (g == 0) {                              // 8 lanes x 16 B = 128 B row
        uint4 r;
        r.x = bfpack2(f0[0] * dd, f0[1] * dd);
        r.y = bfpack2(f0[2] * dd, f0[3] * dd);
        r.z = bfpack2(f0[4] * dd, f0[5] * dd);
        r.w = bfpack2(f0[6] * dd, f0[7] * dd);
        aggb[(size_t)n * 8 + c] = r;
    }
}

// ---------- fused zd = (relu(agg @ W1 + b1) @ W2) * dinv  (tiled GEMM) ------
__global__ __launch_bounds__(256) void k_mlp(const uint4* __restrict__ aggb,
                                             const float* __restrict__ W1,
                                             const float* __restrict__ b1,
                                             const float* __restrict__ W2,
                                             const float* __restrict__ dinv,
                                             float* __restrict__ zd, int n_nodes) {
    __shared__ float sW1[IN_DIM * HID_DIM];   // [k][j] row-major, 32 KB
    __shared__ float sAt[IN_DIM * TILE_N];    // [k][node] transposed, 32 KB
    __shared__ float sW2[HID_DIM];
    __shared__ float sb1[HID_DIM];

    int t = threadIdx.x;
    {
        const float4* W14 = (const float4*)W1;
        float4* sW14 = (float4*)sW1;
        #pragma unroll
        for (int i = 0; i < 8; i++) sW14[t + i * 256] = W14[t + i * 256];
    }
    if (t < HID_DIM) { sW2[t] = W2[t]; sb1[t] = b1[t]; }

    int node0 = blockIdx.x * TILE_N;
    {
        int ln = t >> 1;                       // local node 0..127
        int qh = (t & 1) * 4;                  // uint4 quad half
        int n = node0 + ln;
        #pragma unroll
        for (int q0 = 0; q0 < 4; q0++) {
            int q = qh + q0;
            uint4 u = (n < n_nodes) ? aggb[(size_t)n * 8 + q]
                                    : make_uint4(0, 0, 0, 0);
            int k = q * 8;
            sAt[(k + 0) * TILE_N + ln] = bflo(u.x);
            sAt[(k + 1) * TILE_N + ln] = bfhi(u.x);
            sAt[(k + 2) * TILE_N + ln] = bflo(u.y);
            sAt[(k + 3) * TILE_N + ln] = bfhi(u.y);
            sAt[(k + 4) * TILE_N + ln] = bflo(u.z);
            sAt[(k + 5) * TILE_N + ln] = bfhi(u.z);
            sAt[(k + 6) * TILE_N + ln] = bflo(u.w);
            sAt[(k + 7) * TILE_N + ln] = bfhi(u.w);
        }
    }
    __syncthreads();

    int tx = t & 15;
    int ty = t >> 4;
    float zpart[8] = {0, 0, 0, 0, 0, 0, 0, 0};

    #pragma unroll
    for (int jh = 0; jh < 2; jh++) {
        int jbase = jh * 64 + tx * 4;
        float4 bv = *(const float4*)&sb1[jbase];
        float acc[8][4];
        #pragma unroll
        for (int i = 0; i < 8; i++) {
            acc[i][0] = bv.x; acc[i][1] = bv.y; acc[i][2] = bv.z; acc[i][3] = bv.w;
        }
        #pragma unroll 4
        for (int k = 0; k < IN_DIM; k++) {
            float4 w  = *(const float4*)&sW1[k * HID_DIM + jbase];
            float4 a0 = *(const float4*)&sAt[k * TILE_N + ty * 8];
            float4 a1 = *(const float4*)&sAt[k * TILE_N + ty * 8 + 4];
            float av[8] = {a0.x, a0.y, a0.z, a0.w, a1.x, a1.y, a1.z, a1.w};
            #pragma unroll
            for (int i = 0; i < 8; i++) {
                acc[i][0] += av[i] * w.x;
                acc[i][1] += av[i] * w.y;
                acc[i][2] += av[i] * w.z;
                acc[i][3] += av[i] * w.w;
            }
        }
        float4 w2v = *(const float4*)&sW2[jbase];
        #pragma unroll
        for (int i = 0; i < 8; i++) {
            float s = 0.0f;
            s += (acc[i][0] > 0.f ? acc[i][0] : 0.f) * w2v.x;
            s += (acc[i][1] > 0.f ? acc[i][1] : 0.f) * w2v.y;
            s += (acc[i][2] > 0.f ? acc[i][2] : 0.f) * w2v.z;
            s += (acc[i][3] > 0.f ? acc[i][3] : 0.f) * w2v.w;
            zpart[i] += s;
        }
    }

    #pragma unroll
    for (int m = 1; m < 16; m <<= 1) {
        #pragma unroll
        for (int i = 0; i < 8; i++) zpart[i] += __shfl_xor(zpart[i], m);
    }
    if (tx == 0) {
        #pragma unroll
        for (int i = 0; i < 8; i++) {
            int n = node0 + ty * 8 + i;
            if (n < n_nodes) zd[n] = zpart[i] * dinv[n];
        }
    }
}

// ---------- layer-2 aggregation: 8 lanes per node ----------
__global__ __launch_bounds__(1024, 8) void k_gather1(const int* __restrict__ off,
                                                     const int* __restrict__ nend,
                                                     const int* __restrict__ csr,
                                                     const float* __restrict__ zd,
                                                     const float* __restrict__ dinv,
                                                     const float* __restrict__ b2,
                                                     float* __restrict__ out, int n_nodes) {
    int tid = blockIdx.x * 1024 + threadIdx.x;
    int n = tid >> 3;
    int l = tid & 7;
    if (n >= n_nodes) return;
    int beg = off[n], fin = nend[n];
    float a0 = 0.0f, a1 = 0.0f;
    for (int i = beg + l; i < fin; i += 16) {
        a0 += zd[csr[i]];
        int i2 = i + 8;
        if (i2 < fin) a1 += zd[csr[i2]];
    }
    float a = a0 + a1;
    a += __shfl_xor(a, 1);
    a += __shfl_xor(a, 2);
    a += __shfl_xor(a, 4);
    if (l == 0) out[n] = (a + zd[n]) * dinv[n] + b2[0];
}

extern "C" void kernel_launch(void* const* d_in, const int* in_sizes, int n_in,
                              void* d_out, int out_size, void* d_ws, size_t ws_size,
                              hipStream_t stream) {
    const float* x  = (const float*)d_in[0];
    const int*   ei = (const int*)d_in[1];     // [2, E] int32
    const float* W1 = (const float*)d_in[2];
    const float* b1 = (const float*)d_in[3];
    const float* W2 = (const float*)d_in[4];
    const float* b2 = (const float*)d_in[5];
    float* out = (float*)d_out;

    const int N = NNODES;
    const int E = NEDGES;
    const int* src = ei;
    const int* dst = ei + E;

    // workspace (~34 MB):
    // gbcur | off | nend | dinv | zd | csr[NBUK*BUKCAP] | xsb(bf16) | union(ebuf, aggb)
    int* gbcur = (int*)d_ws;                   // [NBUK] (padded to 512)
    int* off   = gbcur + 512;                  // [N]
    int* nend  = off + N;                      // [N]
    float* dinv = (float*)(nend + N);          // [N]
    float* zd   = dinv + N;                    // [N]
    int* csr    = (int*)(zd + N);              // [NBUK*BUKCAP] gapped (7.2 MB)
    size_t o1 = ((size_t)((char*)(csr + NBUK * BUKCAP) - (char*)d_ws) + 127) & ~(size_t)127;
    unsigned* xsb = (unsigned*)((char*)d_ws + o1);        // [N*32] = 12.8 MB
    size_t o2 = o1 + (size_t)N * 128;
    int*   ebuf = (int*)((char*)d_ws + o2);               // [NBUK*BUKCAP] 7.2 MB
    uint4* aggb = (uint4*)((char*)d_ws + o2);             // [N*8] 12.8 MB (union:
                                                          //  ebuf dies in k_bfill,
                                                          //  aggb born in k_gather64)

    hipMemsetAsync(gbcur, 0, 512 * sizeof(int), stream);
    k_part<<<(E + CHUNK - 1) / CHUNK, 1024, 0, stream>>>(src, dst, gbcur, ebuf, E);
    k_bfill<<<NBUK, 1024, 0, stream>>>(gbcur, ebuf, x, off, nend, dinv, csr, xsb, N);
    k_gather64<<<(N * 64 + 255) / 256, 256, 0, stream>>>(off, nend, csr, (const uint4*)xsb,
                                                         dinv, aggb, N);
    k_mlp<<<(N + TILE_N - 1) / TILE_N, 256, 0, stream>>>(aggb, W1, b1, W2, dinv, zd, N);
    k_gather1<<<(N * 8 + 1023) / 1024, 1024, 0, stream>>>(off, nend, csr, zd, dinv, b2, out, N);
}

// Round 14
// 166.965 us; speedup vs baseline: 1.4326x; 1.1882x over previous
//
#include <hip/hip_runtime.h>
#include <hip/hip_bf16.h>

#define NNODES 100000
#define NEDGES 1600000
#define IN_DIM 64
#define HID_DIM 128

#define BUKSHIFT 8                   // 256 nodes per bucket (best measured geometry)
#define BUKNODES 256
#define NBUK ((NNODES + 255) >> 8)   // 391 buckets
#define BUKCAP 4608                  // mean 4094 + 8 sigma; deterministic input -> safe
#define CHUNK 4096                   // edges per partition block
#define TILE_N 128                   // nodes per k_mlp block
#define W1TS 72                      // W1t row stride (bf16): 64 + 8 pad -> lane banks spread

// Edge packing: src in bits 0..23, dst-within-bucket (8 bits) in 24..31.
#define EPACK(s, d)  ((s) | (((d) & 255) << 24))
#define ESRC(p)      ((p) & 0x00FFFFFF)
#define EDL(p)       ((int)(((unsigned)(p)) >> 24))

typedef __attribute__((ext_vector_type(8))) short short8;   // 8 bf16 = 4 VGPRs
typedef __attribute__((ext_vector_type(4))) float f32x4;

// bf16 helpers (RNE round; unpack = shift/mask only)
__device__ inline unsigned short f2bf(float f) {
    unsigned u = __float_as_uint(f);
    u += 0x7fff + ((u >> 16) & 1);
    return (unsigned short)(u >> 16);
}
__device__ inline unsigned bfpack2(float a, float b) {
    return (unsigned)f2bf(a) | ((unsigned)f2bf(b) << 16);
}
__device__ inline float bflo(unsigned u) { return __uint_as_float(u << 16); }
__device__ inline float bfhi(unsigned u) { return __uint_as_float(u & 0xffff0000u); }

// ---------- phase 1: bucket-partition edges into packed ebuf ----------
__global__ __launch_bounds__(1024, 8) void k_part(const int* __restrict__ src,
                                                  const int* __restrict__ dst,
                                                  int* __restrict__ gbcur,
                                                  int* __restrict__ ebuf, int E) {
    __shared__ int stage[CHUNK];               // 16 KB packed edges
    __shared__ unsigned short bukof[CHUNK];    // 8 KB bucket id per slot
    __shared__ int hist[NBUK];
    __shared__ int scanb[NBUK];
    __shared__ int basep[NBUK];
    __shared__ int sb[2][512];
    int t = threadIdx.x;
    int start = blockIdx.x * CHUNK;
    int n = E - start; if (n > CHUNK) n = CHUNK;

    if (t < NBUK) hist[t] = 0;
    __syncthreads();

    int myb[4], myr[4], mp[4];
    #pragma unroll
    for (int i = 0; i < 4; i++) {
        int c = t + i * 1024;
        if (c < n) {
            int s = src[start + c];
            int d = dst[start + c];
            int b = d >> BUKSHIFT;
            myb[i] = b;
            mp[i]  = EPACK(s, d);
            myr[i] = atomicAdd(&hist[b], 1);   // rank within (block,bucket)
        } else myb[i] = -1;
    }
    __syncthreads();

    // parallel exclusive scan of hist[NBUK] (NBUK=391 < 512)
    {
        int v = (t < NBUK) ? hist[t] : 0;
        if (t < 512) sb[0][t] = v;
        __syncthreads();
        int pin = 0;
        for (int ofs = 1; ofs < 512; ofs <<= 1) {
            if (t < 512) sb[pin ^ 1][t] = (t >= ofs) ? sb[pin][t] + sb[pin][t - ofs]
                                                     : sb[pin][t];
            __syncthreads();
            pin ^= 1;
        }
        if (t < NBUK) scanb[t] = sb[pin][t] - v;
    }

    if (t < NBUK) {                            // claim region space per bucket
        int h = hist[t];
        basep[t] = h ? (t * BUKCAP + atomicAdd(&gbcur[t], h)) : 0;
    }
    __syncthreads();

    #pragma unroll
    for (int i = 0; i < 4; i++) {              // scatter into LDS stage
        if (myb[i] >= 0) {
            int p = scanb[myb[i]] + myr[i];
            stage[p] = mp[i];
            bukof[p] = (unsigned short)myb[i];
        }
    }
    __syncthreads();

    for (int c = t; c < n; c += 1024) {        // positional writeout in runs
        int b = bukof[c];
        ebuf[basep[b] + (c - scanb[b])] = stage[c];
    }
}

// ---------- phase 2: degrees + dinv + off/end + csr fill + x->xsb convert ----
__global__ __launch_bounds__(1024, 8) void k_bfill(const int* __restrict__ gbcur,
                                                   const int* __restrict__ ebuf,
                                                   const float* __restrict__ x,
                                                   int* __restrict__ off,
                                                   int* __restrict__ nend,
                                                   float* __restrict__ dinv,
                                                   int* __restrict__ csr,
                                                   unsigned* __restrict__ xsb, int N) {
    __shared__ int sEdge[BUKCAP];              // 18.4 KB
    __shared__ int lcnt[BUKNODES];
    __shared__ int sbuf[2][BUKNODES];
    __shared__ int cur[BUKNODES];
    __shared__ float sdinv[BUKNODES];
    int b = blockIdx.x, t = threadIdx.x;
    int nbase = b << BUKSHIFT;
    int rbase = b * BUKCAP;
    int cntb = gbcur[b];                       // final bucket edge count
    if (t < BUKNODES) lcnt[t] = 0;
    __syncthreads();
    for (int i = t; i < cntb; i += 1024) {     // load + count in one pass
        int p = ebuf[rbase + i];
        sEdge[i] = p;
        atomicAdd(&lcnt[EDL(p)], 1);
    }
    __syncthreads();
    int v = (t < BUKNODES) ? lcnt[t] : 0;
    if (t < BUKNODES) sbuf[0][t] = v;
    __syncthreads();
    int pin = 0;
    for (int ofs = 1; ofs < BUKNODES; ofs <<= 1) {
        if (t < BUKNODES) sbuf[pin ^ 1][t] = (t >= ofs) ? sbuf[pin][t] + sbuf[pin][t - ofs]
                                                        : sbuf[pin][t];
        __syncthreads();
        pin ^= 1;
    }
    if (t < BUKNODES) {
        int o = rbase + sbuf[pin][t] - v;      // region base + exclusive scan
        int nid = nbase + t;
        float dv = rsqrtf((float)v + 1.0f);
        sdinv[t] = dv;
        if (nid < N) {
            off[nid]  = o;
            nend[nid] = o + v;
            dinv[nid] = dv;
        }
        cur[t] = o;
    }
    __syncthreads();
    for (int i = t; i < cntb; i += 1024) {     // fill csr from LDS
        int p = sEdge[i];
        int pos = atomicAdd(&cur[EDL(p)], 1);
        csr[pos] = ESRC(p);
    }
    // fused convert: xsb[n] = bf16(x[n] * dinv[n]) for this bucket's nodes
    for (int i = t; i < BUKNODES * 16; i += 1024) {
        int nl = i >> 4;
        int nid = nbase + nl;
        if (nid < N) {
            float dv = sdinv[nl];
            float4 vx = ((const float4*)x)[(size_t)nid * 16 + (i & 15)];
            uint2 u;
            u.x = bfpack2(vx.x * dv, vx.y * dv);
            u.y = bfpack2(vx.z * dv, vx.w * dv);
            ((uint2*)xsb)[(size_t)nid * 16 + (i & 15)] = u;
        }
    }
}

// ---------- layer-1 aggregation: wave per node, bf16 rows ----------
// agg[n] = dd * ( xs[n] + sum_s xs[s] ), stored bf16 (contiguous 128 B rows
// == ready-made MFMA A-fragments for k_mlp).
__global__ __launch_bounds__(256) void k_gather64(const int* __restrict__ off,
                                                  const int* __restrict__ nend,
                                                  const int* __restrict__ csr,
                                                  const uint4* __restrict__ xsb,
                                                  const float* __restrict__ dinv,
                                                  uint4* __restrict__ aggb, int n_nodes) {
    int tid = blockIdx.x * 256 + threadIdx.x;
    int n = tid >> 6;                          // wave-uniform node
    if (n >= n_nodes) return;
    int lane = threadIdx.x & 63;
    int c = lane & 7;
    int g = lane >> 3;
    int beg = off[n], fin = nend[n];
    float dd = dinv[n];
    float f0[8] = {0, 0, 0, 0, 0, 0, 0, 0};
    float f1[8] = {0, 0, 0, 0, 0, 0, 0, 0};
    if (g == 0) {                              // self term xs[n]
        uint4 u = xsb[(size_t)n * 8 + c];
        f0[0] = bflo(u.x); f0[1] = bfhi(u.x); f0[2] = bflo(u.y); f0[3] = bfhi(u.y);
        f0[4] = bflo(u.z); f0[5] = bfhi(u.z); f0[6] = bflo(u.w); f0[7] = bfhi(u.w);
    }
    for (int base = beg; base < fin; base += 64) {
        int nn = fin - base; if (nn > 64) nn = 64;
        int idx = (lane < nn) ? csr[base + lane] : 0;
        int j = 0;
        for (; j + 16 <= nn; j += 16) {        // 16 edges: 2 loads in flight
            int sa = __shfl(idx, j + g);
            int sb = __shfl(idx, j + 8 + g);
            uint4 ua = xsb[(size_t)sa * 8 + c];
            uint4 ub = xsb[(size_t)sb * 8 + c];
            f0[0] += bflo(ua.x); f0[1] += bfhi(ua.x); f0[2] += bflo(ua.y); f0[3] += bfhi(ua.y);
            f0[4] += bflo(ua.z); f0[5] += bfhi(ua.z); f0[6] += bflo(ua.w); f0[7] += bfhi(ua.w);
            f1[0] += bflo(ub.x); f1[1] += bfhi(ub.x); f1[2] += bflo(ub.y); f1[3] += bfhi(ub.y);
            f1[4] += bflo(ub.z); f1[5] += bfhi(ub.z); f1[6] += bflo(ub.w); f1[7] += bfhi(ub.w);
        }
        for (; j < nn; j += 8) {               // tail, 8-wide predicated
            int rem = nn - j;
            int sa = __shfl(idx, j + g);
            if (g < rem) {
                uint4 ua = xsb[(size_t)sa * 8 + c];
                f0[0] += bflo(ua.x); f0[1] += bfhi(ua.x); f0[2] += bflo(ua.y); f0[3] += bfhi(ua.y);
                f0[4] += bflo(ua.z); f0[5] += bfhi(ua.z); f0[6] += bflo(ua.w); f0[7] += bfhi(ua.w);
            }
        }
    }
    #pragma unroll
    for (int i = 0; i < 8; i++) f0[i] += f1[i];
    #pragma unroll
    for (int m = 8; m < 64; m <<= 1) {         // combine the 8 g-slots
        #pragma unroll
        for (int i = 0; i < 8; i++) f0[i] += __shfl_xor(f0[i], m);
    }
    if (g == 0) {                              // 8 lanes x 16 B = 128 B row
        uint4 r;
        r.x = bfpack2(f0[0] * dd, f0[1] * dd);
        r.y = bfpack2(f0[2] * dd, f0[3] * dd);
        r.z = bfpack2(f0[4] * dd, f0[5] * dd);
        r.w = bfpack2(f0[6] * dd, f0[7] * dd);
        aggb[(size_t)n * 8 + c] = r;
    }
}

// ---------- MFMA MLP: zd = (relu(agg @ W1 + b1) @ W2) * dinv ----------
// R13's vector-ALU GEMM ran 45.5 us LDS/VALU-bound (384 ds_read_b128/wave,
// 65 KB LDS -> 2 blocks/CU). MFMA version: aggb bf16 rows ARE the A-operand
// fragment (m=lane&15, k=quad*8+j -> one 16 B load); W1 staged bf16
// TRANSPOSED in LDS (stride 72 spreads column reads across banks); 16
// mfma_f32_16x16x32_bf16 per wave. C/D layout (verified m89): col=lane&15,
// row=quad*4+reg. Epilogue relu*W2 in registers, shfl-reduce over cols.
__global__ __launch_bounds__(512) void k_mlp(const uint4* __restrict__ aggb,
                                             const float* __restrict__ W1,
                                             const float* __restrict__ b1,
                                             const float* __restrict__ W2,
                                             const float* __restrict__ dinv,
                                             float* __restrict__ zd, int n_nodes) {
    __shared__ __align__(16) unsigned short sW1t[HID_DIM * W1TS];  // 18.4 KB bf16 [hid][k]
    __shared__ float sW2[HID_DIM];
    __shared__ float sb1[HID_DIM];
    int t = threadIdx.x;
    for (int i = t; i < IN_DIM * HID_DIM; i += 512) {   // W1 [k][hid] -> bf16 [hid][k]
        int k = i >> 7, hid = i & 127;
        sW1t[hid * W1TS + k] = f2bf(W1[i]);
    }
    if (t < HID_DIM) { sW2[t] = W2[t]; sb1[t] = b1[t]; }
    __syncthreads();

    int node0 = blockIdx.x * TILE_N;
    int w = t >> 6;                            // wave -> 16-node tile
    int lane = t & 63;
    int col = lane & 15;
    int quad = lane >> 4;

    // A fragments: node = node0 + w*16 + col, k in [0,64). Clamp OOB rows to 0
    // (their outputs are discarded at store).
    int na = node0 + w * 16 + col;
    int nac = na < n_nodes ? na : 0;
    const short8* arow = (const short8*)(aggb + (size_t)nac * 8);
    short8 a0 = arow[quad];                    // k = quad*8 + j,      K 0..31
    short8 a1 = arow[4 + quad];                // k = 32 + quad*8 + j, K 32..63

    float zpart[4] = {0, 0, 0, 0};
    #pragma unroll
    for (int h0 = 0; h0 < 8; h0++) {           // 8 hidden tiles of 16
        int hid = h0 * 16 + col;
        const short8* brow = (const short8*)(sW1t + hid * W1TS);
        short8 b0 = brow[quad];                // B[k=quad*8+j][n=col] via W1t rows
        short8 b1f = brow[4 + quad];
        f32x4 c = {0.f, 0.f, 0.f, 0.f};
        c = __builtin_amdgcn_mfma_f32_16x16x32_bf16(a0, b0, c, 0, 0, 0);
        c = __builtin_amdgcn_mfma_f32_16x16x32_bf16(a1, b1f, c, 0, 0, 0);
        float bb = sb1[hid], ww = sW2[hid];
        #pragma unroll
        for (int r = 0; r < 4; r++) {          // lane holds rows quad*4+r, col hid
            float v = c[r] + bb;
            zpart[r] += (v > 0.f ? v : 0.f) * ww;
        }
    }
    #pragma unroll
    for (int m = 1; m < 16; m <<= 1) {         // reduce over the 16 hid columns
        #pragma unroll
        for (int r = 0; r < 4; r++) zpart[r] += __shfl_xor(zpart[r], m);
    }
    if (col == 0) {
        #pragma unroll
        for (int r = 0; r < 4; r++) {
            int n = node0 + w * 16 + quad * 4 + r;
            if (n < n_nodes) zd[n] = zpart[r] * dinv[n];   // pre-scaled for layer 2
        }
    }
}

// ---------- layer-2 aggregation: 8 lanes per node ----------
__global__ __launch_bounds__(1024, 8) void k_gather1(const int* __restrict__ off,
                                                     const int* __restrict__ nend,
                                                     const int* __restrict__ csr,
                                                     const float* __restrict__ zd,
                                                     const float* __restrict__ dinv,
                                                     const float* __restrict__ b2,
                                                     float* __restrict__ out, int n_nodes) {
    int tid = blockIdx.x * 1024 + threadIdx.x;
    int n = tid >> 3;
    int l = tid & 7;
    if (n >= n_nodes) return;
    int beg = off[n], fin = nend[n];
    float a0 = 0.0f, a1 = 0.0f;
    for (int i = beg + l; i < fin; i += 16) {
        a0 += zd[csr[i]];
        int i2 = i + 8;
        if (i2 < fin) a1 += zd[csr[i2]];
    }
    float a = a0 + a1;
    a += __shfl_xor(a, 1);
    a += __shfl_xor(a, 2);
    a += __shfl_xor(a, 4);
    if (l == 0) out[n] = (a + zd[n]) * dinv[n] + b2[0];
}

extern "C" void kernel_launch(void* const* d_in, const int* in_sizes, int n_in,
                              void* d_out, int out_size, void* d_ws, size_t ws_size,
                              hipStream_t stream) {
    const float* x  = (const float*)d_in[0];
    const int*   ei = (const int*)d_in[1];     // [2, E] int32
    const float* W1 = (const float*)d_in[2];
    const float* b1 = (const float*)d_in[3];
    const float* W2 = (const float*)d_in[4];
    const float* b2 = (const float*)d_in[5];
    float* out = (float*)d_out;

    const int N = NNODES;
    const int E = NEDGES;
    const int* src = ei;
    const int* dst = ei + E;

    // workspace (~34 MB):
    // gbcur | off | nend | dinv | zd | csr[NBUK*BUKCAP] | xsb(bf16) | union(ebuf, aggb)
    int* gbcur = (int*)d_ws;                   // [NBUK] (padded to 512)
    int* off   = gbcur + 512;                  // [N]
    int* nend  = off + N;                      // [N]
    float* dinv = (float*)(nend + N);          // [N]
    float* zd   = dinv + N;                    // [N]
    int* csr    = (int*)(zd + N);              // [NBUK*BUKCAP] gapped (7.2 MB)
    size_t o1 = ((size_t)((char*)(csr + NBUK * BUKCAP) - (char*)d_ws) + 127) & ~(size_t)127;
    unsigned* xsb = (unsigned*)((char*)d_ws + o1);        // [N*32] = 12.8 MB
    size_t o2 = o1 + (size_t)N * 128;
    int*   ebuf = (int*)((char*)d_ws + o2);               // [NBUK*BUKCAP] 7.2 MB
    uint4* aggb = (uint4*)((char*)d_ws + o2);             // [N*8] 12.8 MB (union:
                                                          //  ebuf dies in k_bfill,
                                                          //  aggb born in k_gather64)

    hipMemsetAsync(gbcur, 0, 512 * sizeof(int), stream);
    k_part<<<(E + CHUNK - 1) / CHUNK, 1024, 0, stream>>>(src, dst, gbcur, ebuf, E);
    k_bfill<<<NBUK, 1024, 0, stream>>>(gbcur, ebuf, x, off, nend, dinv, csr, xsb, N);
    k_gather64<<<(N * 64 + 255) / 256, 256, 0, stream>>>(off, nend, csr, (const uint4*)xsb,
                                                         dinv, aggb, N);
    k_mlp<<<(N + TILE_N - 1) / TILE_N, 512, 0, stream>>>(aggb, W1, b1, W2, dinv, zd, N);
    k_gather1<<<(N * 8 + 1023) / 1024, 1024, 0, stream>>>(off, nend, csr, zd, dinv, b2, out, N);
}